// Round 16
// baseline (417.274 us; speedup 1.0000x reference)
//
#include <hip/hip_runtime.h>
#include <stdint.h>

// Problem dims (fixed)
constexpr int T_DIM   = 16384;
constexpr int IN_DIM  = 4096;
constexpr int OUT_DIM = 4096;

using int32x4  = __attribute__((ext_vector_type(4)))  int;
using int32x16 = __attribute__((ext_vector_type(16))) int;

#define GLOAD_LDS16(g, l)                                                     \
    __builtin_amdgcn_global_load_lds(                                         \
        (const __attribute__((address_space(1))) void*)(uintptr_t)(g),        \
        (__attribute__((address_space(3))) void*)(uintptr_t)(l), 16, 0, 0)

// ===========================================================================
// Pre-pass: int32 (int8-valued) -> packed int8 in FRAGMENT-MAJOR order for
// the 32x32x32 MFMA: 1KB block per (row_tile = row>>5, k_tile = k>>5);
// within block, byte offset = ((k>>4)&1)*512 + (row&31)*16 + (k&15)
// == lane*16 for lane = khalf*32 + (row&31) — exactly the MFMA operand
// order. GEMM then ds_reads base + lane*16 + imm (lane-linear, 8 lanes span
// all 32 banks once: conflict-free by construction; R12's row-indexed read
// measured 2.5e7 conflicts). Bijective chunk permutation.
// ===========================================================================
__global__ void pack_fm(const int* __restrict__ src, int8_t* __restrict__ dst,
                        int rows, int cols) {
    int64_t tid = (int64_t)blockIdx.x * blockDim.x + threadIdx.x;
    int64_t nchunks = (int64_t)rows * (cols / 16);
    if (tid >= nchunks) return;
    int row = (int)(tid / (cols / 16));
    int kc  = (int)(tid % (cols / 16));   // 16-byte k-chunk index
    const int32x4* s4 =
        reinterpret_cast<const int32x4*>(src + (int64_t)row * cols + (kc << 4));
    uint32_t p[4];
#pragma unroll
    for (int v = 0; v < 4; ++v) {
        int32x4 t = s4[v];
        p[v] = (uint32_t)(t[0] & 0xff) | ((uint32_t)(t[1] & 0xff) << 8) |
               ((uint32_t)(t[2] & 0xff) << 16) | ((uint32_t)(t[3] & 0xff) << 24);
    }
    const int64_t blk = (int64_t)(row >> 5) * (cols >> 5) + (kc >> 1);
    const int64_t off = blk * 1024 + (kc & 1) * 512 + (row & 31) * 16;
    *reinterpret_cast<int32x4*>(dst + off) = *reinterpret_cast<int32x4*>(p);
}

// ===========================================================================
// Main GEMM — ROUND 13: R12 (mfma_i32_32x32x32_i8, BK=128, 2x64KB buffers,
// stage->other-buf + vmcnt(0)+barrier) with the LDS layout swapped to
// fragment-major (see pack_fm). Single-variable change vs R12:
//   - ds_read: one shared vaddr (lane*16) + compile-time immediate per
//     (m,ks) block -> conflict-free + near-zero addressing VALU.
//   - staging: each wave's global_load_lds covers exactly one contiguous
//     1KB block (lane-linear on both sides); 8 ptrs advance +4KB/tile.
// A-LDS: 8 row-tiles x 4 k-tiles x 1KB = 32KB; B-LDS same, at +ATILE.
// Verified pieces kept: 32x32 operand & C/D layouts (R12 passed absmax),
// boundary bookkeeping (R9), XCD swizzle, epilogue.
// ===========================================================================
constexpr int BM = 256, BN = 256, BK = 128;
constexpr int NT    = IN_DIM / BK;     // 32
constexpr int ATILE = BM * BK;         // 32 KiB
constexpr int BUFSZ = 2 * ATILE;       // 64 KiB (A + B)

__global__ __launch_bounds__(512, 2)
void gemm_i8_fm(const int8_t* __restrict__ x8p, const int8_t* __restrict__ w8p,
                const int* __restrict__ bias, const float* __restrict__ alphap,
                const float* __restrict__ betap, int* __restrict__ out) {
    __shared__ __align__(16) int8_t lds[2 * BUFSZ];   // 128 KiB

    const int tid  = threadIdx.x;
    const int lane = tid & 63;
    const int wid  = tid >> 6;
    const int wr   = wid >> 2;   // 0..1 (M)
    const int wc   = wid & 3;    // 0..3 (N)

    // XCD-chunked bijective swizzle (nwg = 1024, %8==0)
    const int nwg = gridDim.x;
    const int cpx = nwg >> 3;
    const int bid = blockIdx.x;
    const int swz = (bid & 7) * cpx + (bid >> 3);
    const int bm  = swz >> 4;    // 64 M-blocks
    const int bn  = swz & 15;    // 16 N-blocks
    const int brow = bm * BM;
    const int bcol = bn * BN;

    const float alpha = *alphap;
    const float beta  = *betap;

    const int lrow  = lane & 31;   // row (A) / col (B) within fragment
    const int khalf = lane >> 5;

    // ---- staging: wave w, load j covers LDS block b = j*8 + w (b: rt*4+kt).
    // Global block for tile t: ((brow>>5)+rt)*(IN_DIM>>5) + t*4 + kt, 1KB,
    // lane-linear inside. Pointers advance +4096 per tile.
    constexpr int KT_ROW = IN_DIM >> 5;   // 128 k-tiles per row-tile
    const int8_t* pA[4];
    const int8_t* pB[4];
    int dA[4], dB[4];
#pragma unroll
    for (int j = 0; j < 4; ++j) {
        const int b  = j * 8 + wid;       // 0..31
        const int rt = b >> 2, kt = b & 3;
        pA[j] = x8p + ((int64_t)((brow >> 5) + rt) * KT_ROW + kt) * 1024 + lane * 16;
        pB[j] = w8p + ((int64_t)((bcol >> 5) + rt) * KT_ROW + kt) * 1024 + lane * 16;
        dA[j] = b * 1024 + lane * 16;
        dB[j] = ATILE + b * 1024 + lane * 16;
    }

    // ---- ds_read bases (lane-linear; per-(m,ks) immediate added below)
    // A frag (m,ks): block wr*16 + m*4 + ks; B frag (n,ks): block wc*8 + n*4 + ks.
    const int abase = (wr << 14) + lane * 16;           // wr*16*1024
    const int bbase = ATILE + (wc << 13) + lane * 16;   // wc*8*1024

    int32x16 acc[4][2] = {};

#define STAGE8(DSTB)                                                          \
    do {                                                                      \
        int8_t* nb = lds + (DSTB) * BUFSZ;                                    \
        _Pragma("unroll") for (int j = 0; j < 4; ++j) {                       \
            GLOAD_LDS16(pA[j], nb + dA[j]);                                   \
            GLOAD_LDS16(pB[j], nb + dB[j]);                                   \
            pA[j] += 4096; pB[j] += 4096;                                     \
        }                                                                     \
    } while (0)

    // Tile body: stage t+1, 4 ks-steps of {6 reads (imm offsets) + 8 MFMA},
    // then vmcnt(0)+barrier boundary.
#define TILE(RB, SB, PF, LAST)                                                \
    do {                                                                      \
        const int8_t* rb = lds + (RB) * BUFSZ;                                \
        if (PF) STAGE8(SB);                                                   \
        _Pragma("unroll") for (int ks = 0; ks < 4; ++ks) {                    \
            int32x4 bf0 = *reinterpret_cast<const int32x4*>(                  \
                rb + bbase + (0 * 4 + ks) * 1024);                            \
            int32x4 bf1 = *reinterpret_cast<const int32x4*>(                  \
                rb + bbase + (1 * 4 + ks) * 1024);                            \
            int32x4 af[4];                                                    \
            _Pragma("unroll") for (int m = 0; m < 4; ++m)                     \
                af[m] = *reinterpret_cast<const int32x4*>(                    \
                    rb + abase + (m * 4 + ks) * 1024);                        \
            __builtin_amdgcn_s_setprio(1);                                    \
            _Pragma("unroll") for (int m = 0; m < 4; ++m) {                   \
                acc[m][0] = __builtin_amdgcn_mfma_i32_32x32x32_i8(            \
                    af[m], bf0, acc[m][0], 0, 0, 0);                          \
                acc[m][1] = __builtin_amdgcn_mfma_i32_32x32x32_i8(            \
                    af[m], bf1, acc[m][1], 0, 0, 0);                          \
            }                                                                 \
            __builtin_amdgcn_s_setprio(0);                                    \
        }                                                                     \
        if (!(LAST)) {                                                        \
            asm volatile("s_waitcnt vmcnt(0)" ::: "memory");                  \
            __builtin_amdgcn_s_barrier();                                     \
            asm volatile("" ::: "memory");                                    \
        }                                                                     \
    } while (0)

    // Prologue: stage tile 0 -> buf0, drain, publish.
    STAGE8(0);
    asm volatile("s_waitcnt vmcnt(0)" ::: "memory");
    __builtin_amdgcn_s_barrier();
    asm volatile("" ::: "memory");

    // Main loop: tiles 0..29 (15 iters x 2 tiles, literal buffer indices).
#pragma unroll 1
    for (int tt = 0; tt < NT - 2; tt += 2) {
        TILE(0, 1, true, false);
        TILE(1, 0, true, false);
    }
    TILE(0, 1, true,  false);   // t = 30, stages tile 31 -> buf1
    TILE(1, 0, false, true);    // t = 31, no stage, no boundary
#undef TILE
#undef STAGE8

    // Epilogue (verified R12): y = acc*alpha + bias*beta, round, clip, int32.
    // C/D 32x32: col = lane&31, row = (reg&3) + 8*(reg>>2) + 4*khalf.
#pragma unroll
    for (int n = 0; n < 2; ++n) {
        const int col = bcol + wc * 64 + n * 32 + lrow;
        const float bterm = (float)bias[col] * beta;
#pragma unroll
        for (int m = 0; m < 4; ++m) {
            const int rbase = brow + wr * 128 + m * 32 + khalf * 4;
#pragma unroll
            for (int q = 0; q < 4; ++q) {
#pragma unroll
                for (int j = 0; j < 4; ++j) {
                    float y = (float)acc[m][n][q * 4 + j] * alpha + bterm;
                    y = rintf(y);
                    y = fminf(fmaxf(y, -128.0f), 127.0f);
                    out[(int64_t)(rbase + q * 8 + j) * OUT_DIM + col] = (int)y;
                }
            }
        }
    }
}

// ===========================================================================
// Fallback (ws too small): reads int32 inputs directly, packs in regs,
// swizzled ds_write. 128x128 tile, 16x16x64 MFMA. Known-correct (round 2).
// ===========================================================================
__global__ __launch_bounds__(256)
void gemm_i8_fb(const int* __restrict__ x32, const int* __restrict__ w32,
                const int* __restrict__ bias, const float* __restrict__ alphap,
                const float* __restrict__ betap, int* __restrict__ out) {
    constexpr int FBM = 128, FBK = 128;
    __shared__ int8_t lA[FBM * FBK];
    __shared__ int8_t lB[FBM * FBK];

    const int tid  = threadIdx.x;
    const int wid  = tid >> 6;
    const int lane = tid & 63;
    const int nwg = gridDim.x;
    const int cpx = nwg >> 3;
    const int bid = blockIdx.x;
    const int swz = (bid & 7) * cpx + (bid >> 3);
    const int brow = (swz >> 5) * FBM;
    const int bcol = (swz & 31) * FBM;
    const int wr = wid >> 1, wc = wid & 1;
    const float alpha = *alphap;
    const float beta  = *betap;

    int32x4 acc[4][4] = {};
    for (int kt = 0; kt < IN_DIM / FBK; ++kt) {
        const int64_t kbase = (int64_t)kt * FBK;
#pragma unroll
        for (int q = 0; q < 4; ++q) {
            const int off = wid * 4096 + q * 1024 + lane * 16;
            const int row = off >> 7;
            const int k   = off & 127;
            const int* ga = x32 + (int64_t)(brow + row) * IN_DIM + kbase + k;
            const int* gb = w32 + (int64_t)(bcol + row) * IN_DIM + kbase + k;
            uint32_t pa[4], pb[4];
#pragma unroll
            for (int v = 0; v < 4; ++v) {
                int32x4 ta = reinterpret_cast<const int32x4*>(ga)[v];
                int32x4 tb = reinterpret_cast<const int32x4*>(gb)[v];
                pa[v] = (uint32_t)(ta[0] & 0xff) | ((uint32_t)(ta[1] & 0xff) << 8) |
                        ((uint32_t)(ta[2] & 0xff) << 16) | ((uint32_t)(ta[3] & 0xff) << 24);
                pb[v] = (uint32_t)(tb[0] & 0xff) | ((uint32_t)(tb[1] & 0xff) << 8) |
                        ((uint32_t)(tb[2] & 0xff) << 16) | ((uint32_t)(tb[3] & 0xff) << 24);
            }
            const int sc = ((k >> 4) ^ (row & 7)) << 4;
            *reinterpret_cast<int32x4*>(lA + row * FBK + sc) = *reinterpret_cast<int32x4*>(pa);
            *reinterpret_cast<int32x4*>(lB + row * FBK + sc) = *reinterpret_cast<int32x4*>(pb);
        }
        __syncthreads();
#pragma unroll
        for (int ks = 0; ks < 2; ++ks) {
            const int gg = lane >> 4, rr = lane & 15;
            const int lc = ks * 4 + gg;
            int32x4 af[4], bf[4];
#pragma unroll
            for (int m = 0; m < 4; ++m) {
                const int row = wr * 64 + m * 16 + rr;
                af[m] = *reinterpret_cast<const int32x4*>(lA + row * FBK + ((lc ^ (row & 7)) << 4));
            }
#pragma unroll
            for (int n = 0; n < 4; ++n) {
                const int row = wc * 64 + n * 16 + rr;
                bf[n] = *reinterpret_cast<const int32x4*>(lB + row * FBK + ((lc ^ (row & 7)) << 4));
            }
#pragma unroll
            for (int m = 0; m < 4; ++m)
#pragma unroll
                for (int n = 0; n < 4; ++n)
                    acc[m][n] = __builtin_amdgcn_mfma_i32_16x16x64_i8(af[m], bf[n], acc[m][n], 0, 0, 0);
        }
        __syncthreads();
    }
    const int r4 = (lane >> 4) * 4;
    const int cl = lane & 15;
#pragma unroll
    for (int n = 0; n < 4; ++n) {
        const int col = bcol + wc * 64 + n * 16 + cl;
        const float bterm = (float)bias[col] * beta;
#pragma unroll
        for (int m = 0; m < 4; ++m) {
            const int row0 = brow + wr * 64 + m * 16 + r4;
#pragma unroll
            for (int j = 0; j < 4; ++j) {
                float y = (float)acc[m][n][j] * alpha + bterm;
                y = rintf(y);
                y = fminf(fmaxf(y, -128.0f), 127.0f);
                out[(int64_t)(row0 + j) * OUT_DIM + col] = (int)y;
            }
        }
    }
}

// ===========================================================================
extern "C" void kernel_launch(void* const* d_in, const int* in_sizes, int n_in,
                              void* d_out, int out_size, void* d_ws, size_t ws_size,
                              hipStream_t stream) {
    const int*   x     = (const int*)d_in[0];
    const int*   w     = (const int*)d_in[1];
    const int*   bias  = (const int*)d_in[2];
    const float* alpha = (const float*)d_in[3];
    const float* beta  = (const float*)d_in[4];
    int*         out   = (int*)d_out;

    const size_t need = (size_t)T_DIM * IN_DIM + (size_t)OUT_DIM * IN_DIM;

    if (ws_size >= need) {
        int8_t* x8p = (int8_t*)d_ws;
        int8_t* w8p = x8p + (size_t)T_DIM * IN_DIM;
        {
            int64_t nch = (int64_t)T_DIM * (IN_DIM / 16);
            pack_fm<<<(int)((nch + 255) / 256), 256, 0, stream>>>(x, x8p, T_DIM, IN_DIM);
        }
        {
            int64_t nch = (int64_t)OUT_DIM * (IN_DIM / 16);
            pack_fm<<<(int)((nch + 255) / 256), 256, 0, stream>>>(w, w8p, OUT_DIM, IN_DIM);
        }
        const int grid = (T_DIM / BM) * (OUT_DIM / BN);  // 1024
        gemm_i8_fm<<<grid, 512, 0, stream>>>(x8p, w8p, bias, alpha, beta, out);
    } else {
        const int grid = (T_DIM / 128) * (OUT_DIM / 128);  // 4096
        gemm_i8_fb<<<grid, 256, 0, stream>>>(x, w, bias, alpha, beta, out);
    }
}

// Round 17
// 375.659 us; speedup vs baseline: 1.1108x; 1.1108x over previous
//
#include <hip/hip_runtime.h>
#include <stdint.h>

// Problem dims (fixed)
constexpr int T_DIM   = 16384;
constexpr int IN_DIM  = 4096;
constexpr int OUT_DIM = 4096;

using int32x4  = __attribute__((ext_vector_type(4)))  int;
using int32x16 = __attribute__((ext_vector_type(16))) int;

#define GLOAD_LDS16(g, l)                                                     \
    __builtin_amdgcn_global_load_lds(                                         \
        (const __attribute__((address_space(1))) void*)(uintptr_t)(g),        \
        (__attribute__((address_space(3))) void*)(uintptr_t)(l), 16, 0, 0)

// ===========================================================================
// Pre-pass: int32 (int8-valued) -> packed int8 in FRAGMENT-MAJOR order for
// the 32x32x32 MFMA. ROUND 14: tid = OUTPUT chunk (writes fully coalesced,
// 1KB/wave contiguous; R13's output-scattered version cost ~107us vs ~63).
// Reads: 16 consecutive int32 (64B, sector-aligned) per thread at 16KB
// stride across threads — full HBM sector efficiency.
// Layout (unchanged from R13, GEMM-verified): 1KB block per
// (row_tile = row>>5, k_tile = k>>5); inside, off = lane*16 where
// lane = ((k>>4)&1)*32 + (row&31) — exactly the MFMA operand order.
// ===========================================================================
__global__ void pack_fm(const int* __restrict__ src, int8_t* __restrict__ dst,
                        int rows, int cols) {
    int64_t tid = (int64_t)blockIdx.x * blockDim.x + threadIdx.x;   // out chunk
    int64_t nchunks = (int64_t)rows * (cols / 16);
    if (tid >= nchunks) return;
    const int ktiles = cols >> 5;              // k-tiles per row-tile (128)
    const int64_t blk = tid >> 6;              // 1KB output block
    const int     l   = (int)(tid & 63);       // lane slot in block
    const int rt    = (int)(blk / ktiles);
    const int kt    = (int)(blk % ktiles);
    const int khalf = l >> 5;
    const int r     = l & 31;
    const int row    = rt * 32 + r;
    const int kstart = kt * 32 + khalf * 16;   // int32 index
    const int* s = src + (int64_t)row * cols + kstart;
    uint32_t p[4];
#pragma unroll
    for (int v = 0; v < 4; ++v) {
        int32x4 t = reinterpret_cast<const int32x4*>(s)[v];
        p[v] = (uint32_t)(t[0] & 0xff) | ((uint32_t)(t[1] & 0xff) << 8) |
               ((uint32_t)(t[2] & 0xff) << 16) | ((uint32_t)(t[3] & 0xff) << 24);
    }
    *reinterpret_cast<int32x4*>(dst + tid * 16) = *reinterpret_cast<int32x4*>(p);
}

// ===========================================================================
// Main GEMM — unchanged from R13 (verified, 310us, MfmaUtil 41.4, 0 bank
// conflicts): mfma_i32_32x32x32_i8, BK=128, 2x64KB LDS buffers, fragment-
// major LDS (ds_read = shared lane*16 vaddr + compile-time immediates),
// stage->other-buf at tile top + vmcnt(0)+barrier boundary.
// Serial-law status: MFMA 2611 + LDS-read ~2300 + DMA ~500 cy/tile,
// additive and schedule-robust (R3-R13); 24 reads/wave/tile is minimal
// for a 128-AGPR accumulator. This kernel is ~95% of that floor.
// ===========================================================================
constexpr int BM = 256, BN = 256, BK = 128;
constexpr int NT    = IN_DIM / BK;     // 32
constexpr int ATILE = BM * BK;         // 32 KiB
constexpr int BUFSZ = 2 * ATILE;       // 64 KiB (A + B)

__global__ __launch_bounds__(512, 2)
void gemm_i8_fm(const int8_t* __restrict__ x8p, const int8_t* __restrict__ w8p,
                const int* __restrict__ bias, const float* __restrict__ alphap,
                const float* __restrict__ betap, int* __restrict__ out) {
    __shared__ __align__(16) int8_t lds[2 * BUFSZ];   // 128 KiB

    const int tid  = threadIdx.x;
    const int lane = tid & 63;
    const int wid  = tid >> 6;
    const int wr   = wid >> 2;   // 0..1 (M)
    const int wc   = wid & 3;    // 0..3 (N)

    // XCD-chunked bijective swizzle (nwg = 1024, %8==0)
    const int nwg = gridDim.x;
    const int cpx = nwg >> 3;
    const int bid = blockIdx.x;
    const int swz = (bid & 7) * cpx + (bid >> 3);
    const int bm  = swz >> 4;    // 64 M-blocks
    const int bn  = swz & 15;    // 16 N-blocks
    const int brow = bm * BM;
    const int bcol = bn * BN;

    const float alpha = *alphap;
    const float beta  = *betap;

    const int lrow  = lane & 31;   // row (A) / col (B) within fragment
    const int khalf = lane >> 5;

    // ---- staging: wave w, load j covers LDS block b = j*8 + w (b: rt*4+kt).
    constexpr int KT_ROW = IN_DIM >> 5;   // 128 k-tiles per row-tile
    const int8_t* pA[4];
    const int8_t* pB[4];
    int dA[4], dB[4];
#pragma unroll
    for (int j = 0; j < 4; ++j) {
        const int b  = j * 8 + wid;       // 0..31
        const int rt = b >> 2, kt = b & 3;
        pA[j] = x8p + ((int64_t)((brow >> 5) + rt) * KT_ROW + kt) * 1024 + lane * 16;
        pB[j] = w8p + ((int64_t)((bcol >> 5) + rt) * KT_ROW + kt) * 1024 + lane * 16;
        dA[j] = b * 1024 + lane * 16;
        dB[j] = ATILE + b * 1024 + lane * 16;
    }

    // ---- ds_read bases (lane-linear; per-(m,ks) immediate added below)
    const int abase = (wr << 14) + lane * 16;           // wr*16*1024
    const int bbase = ATILE + (wc << 13) + lane * 16;   // wc*8*1024

    int32x16 acc[4][2] = {};

#define STAGE8(DSTB)                                                          \
    do {                                                                      \
        int8_t* nb = lds + (DSTB) * BUFSZ;                                    \
        _Pragma("unroll") for (int j = 0; j < 4; ++j) {                       \
            GLOAD_LDS16(pA[j], nb + dA[j]);                                   \
            GLOAD_LDS16(pB[j], nb + dB[j]);                                   \
            pA[j] += 4096; pB[j] += 4096;                                     \
        }                                                                     \
    } while (0)

#define TILE(RB, SB, PF, LAST)                                                \
    do {                                                                      \
        const int8_t* rb = lds + (RB) * BUFSZ;                                \
        if (PF) STAGE8(SB);                                                   \
        _Pragma("unroll") for (int ks = 0; ks < 4; ++ks) {                    \
            int32x4 bf0 = *reinterpret_cast<const int32x4*>(                  \
                rb + bbase + (0 * 4 + ks) * 1024);                            \
            int32x4 bf1 = *reinterpret_cast<const int32x4*>(                  \
                rb + bbase + (1 * 4 + ks) * 1024);                            \
            int32x4 af[4];                                                    \
            _Pragma("unroll") for (int m = 0; m < 4; ++m)                     \
                af[m] = *reinterpret_cast<const int32x4*>(                    \
                    rb + abase + (m * 4 + ks) * 1024);                        \
            __builtin_amdgcn_s_setprio(1);                                    \
            _Pragma("unroll") for (int m = 0; m < 4; ++m) {                   \
                acc[m][0] = __builtin_amdgcn_mfma_i32_32x32x32_i8(            \
                    af[m], bf0, acc[m][0], 0, 0, 0);                          \
                acc[m][1] = __builtin_amdgcn_mfma_i32_32x32x32_i8(            \
                    af[m], bf1, acc[m][1], 0, 0, 0);                          \
            }                                                                 \
            __builtin_amdgcn_s_setprio(0);                                    \
        }                                                                     \
        if (!(LAST)) {                                                        \
            asm volatile("s_waitcnt vmcnt(0)" ::: "memory");                  \
            __builtin_amdgcn_s_barrier();                                     \
            asm volatile("" ::: "memory");                                    \
        }                                                                     \
    } while (0)

    // Prologue: stage tile 0 -> buf0, drain, publish.
    STAGE8(0);
    asm volatile("s_waitcnt vmcnt(0)" ::: "memory");
    __builtin_amdgcn_s_barrier();
    asm volatile("" ::: "memory");

    // Main loop: tiles 0..29 (15 iters x 2 tiles, literal buffer indices).
#pragma unroll 1
    for (int tt = 0; tt < NT - 2; tt += 2) {
        TILE(0, 1, true, false);
        TILE(1, 0, true, false);
    }
    TILE(0, 1, true,  false);   // t = 30, stages tile 31 -> buf1
    TILE(1, 0, false, true);    // t = 31, no stage, no boundary
#undef TILE
#undef STAGE8

    // Epilogue (verified): y = acc*alpha + bias*beta, round, clip, int32.
    // C/D 32x32: col = lane&31, row = (reg&3) + 8*(reg>>2) + 4*khalf.
#pragma unroll
    for (int n = 0; n < 2; ++n) {
        const int col = bcol + wc * 64 + n * 32 + lrow;
        const float bterm = (float)bias[col] * beta;
#pragma unroll
        for (int m = 0; m < 4; ++m) {
            const int rbase = brow + wr * 128 + m * 32 + khalf * 4;
#pragma unroll
            for (int q = 0; q < 4; ++q) {
#pragma unroll
                for (int j = 0; j < 4; ++j) {
                    float y = (float)acc[m][n][q * 4 + j] * alpha + bterm;
                    y = rintf(y);
                    y = fminf(fmaxf(y, -128.0f), 127.0f);
                    out[(int64_t)(rbase + q * 8 + j) * OUT_DIM + col] = (int)y;
                }
            }
        }
    }
}

// ===========================================================================
// Fallback (ws too small): reads int32 inputs directly, packs in regs,
// swizzled ds_write. 128x128 tile, 16x16x64 MFMA. Known-correct (round 2).
// ===========================================================================
__global__ __launch_bounds__(256)
void gemm_i8_fb(const int* __restrict__ x32, const int* __restrict__ w32,
                const int* __restrict__ bias, const float* __restrict__ alphap,
                const float* __restrict__ betap, int* __restrict__ out) {
    constexpr int FBM = 128, FBK = 128;
    __shared__ int8_t lA[FBM * FBK];
    __shared__ int8_t lB[FBM * FBK];

    const int tid  = threadIdx.x;
    const int wid  = tid >> 6;
    const int lane = tid & 63;
    const int nwg = gridDim.x;
    const int cpx = nwg >> 3;
    const int bid = blockIdx.x;
    const int swz = (bid & 7) * cpx + (bid >> 3);
    const int brow = (swz >> 5) * FBM;
    const int bcol = (swz & 31) * FBM;
    const int wr = wid >> 1, wc = wid & 1;
    const float alpha = *alphap;
    const float beta  = *betap;

    int32x4 acc[4][4] = {};
    for (int kt = 0; kt < IN_DIM / FBK; ++kt) {
        const int64_t kbase = (int64_t)kt * FBK;
#pragma unroll
        for (int q = 0; q < 4; ++q) {
            const int off = wid * 4096 + q * 1024 + lane * 16;
            const int row = off >> 7;
            const int k   = off & 127;
            const int* ga = x32 + (int64_t)(brow + row) * IN_DIM + kbase + k;
            const int* gb = w32 + (int64_t)(bcol + row) * IN_DIM + kbase + k;
            uint32_t pa[4], pb[4];
#pragma unroll
            for (int v = 0; v < 4; ++v) {
                int32x4 ta = reinterpret_cast<const int32x4*>(ga)[v];
                int32x4 tb = reinterpret_cast<const int32x4*>(gb)[v];
                pa[v] = (uint32_t)(ta[0] & 0xff) | ((uint32_t)(ta[1] & 0xff) << 8) |
                        ((uint32_t)(ta[2] & 0xff) << 16) | ((uint32_t)(ta[3] & 0xff) << 24);
                pb[v] = (uint32_t)(tb[0] & 0xff) | ((uint32_t)(tb[1] & 0xff) << 8) |
                        ((uint32_t)(tb[2] & 0xff) << 16) | ((uint32_t)(tb[3] & 0xff) << 24);
            }
            const int sc = ((k >> 4) ^ (row & 7)) << 4;
            *reinterpret_cast<int32x4*>(lA + row * FBK + sc) = *reinterpret_cast<int32x4*>(pa);
            *reinterpret_cast<int32x4*>(lB + row * FBK + sc) = *reinterpret_cast<int32x4*>(pb);
        }
        __syncthreads();
#pragma unroll
        for (int ks = 0; ks < 2; ++ks) {
            const int gg = lane >> 4, rr = lane & 15;
            const int lc = ks * 4 + gg;
            int32x4 af[4], bf[4];
#pragma unroll
            for (int m = 0; m < 4; ++m) {
                const int row = wr * 64 + m * 16 + rr;
                af[m] = *reinterpret_cast<const int32x4*>(lA + row * FBK + ((lc ^ (row & 7)) << 4));
            }
#pragma unroll
            for (int n = 0; n < 4; ++n) {
                const int row = wc * 64 + n * 16 + rr;
                bf[n] = *reinterpret_cast<const int32x4*>(lB + row * FBK + ((lc ^ (row & 7)) << 4));
            }
#pragma unroll
            for (int m = 0; m < 4; ++m)
#pragma unroll
                for (int n = 0; n < 4; ++n)
                    acc[m][n] = __builtin_amdgcn_mfma_i32_16x16x64_i8(af[m], bf[n], acc[m][n], 0, 0, 0);
        }
        __syncthreads();
    }
    const int r4 = (lane >> 4) * 4;
    const int cl = lane & 15;
#pragma unroll
    for (int n = 0; n < 4; ++n) {
        const int col = bcol + wc * 64 + n * 16 + cl;
        const float bterm = (float)bias[col] * beta;
#pragma unroll
        for (int m = 0; m < 4; ++m) {
            const int row0 = brow + wr * 64 + m * 16 + r4;
#pragma unroll
            for (int j = 0; j < 4; ++j) {
                float y = (float)acc[m][n][j] * alpha + bterm;
                y = rintf(y);
                y = fminf(fmaxf(y, -128.0f), 127.0f);
                out[(int64_t)(row0 + j) * OUT_DIM + col] = (int)y;
            }
        }
    }
}

// ===========================================================================
extern "C" void kernel_launch(void* const* d_in, const int* in_sizes, int n_in,
                              void* d_out, int out_size, void* d_ws, size_t ws_size,
                              hipStream_t stream) {
    const int*   x     = (const int*)d_in[0];
    const int*   w     = (const int*)d_in[1];
    const int*   bias  = (const int*)d_in[2];
    const float* alpha = (const float*)d_in[3];
    const float* beta  = (const float*)d_in[4];
    int*         out   = (int*)d_out;

    const size_t need = (size_t)T_DIM * IN_DIM + (size_t)OUT_DIM * IN_DIM;

    if (ws_size >= need) {
        int8_t* x8p = (int8_t*)d_ws;
        int8_t* w8p = x8p + (size_t)T_DIM * IN_DIM;
        {
            int64_t nch = (int64_t)T_DIM * (IN_DIM / 16);
            pack_fm<<<(int)((nch + 255) / 256), 256, 0, stream>>>(x, x8p, T_DIM, IN_DIM);
        }
        {
            int64_t nch = (int64_t)OUT_DIM * (IN_DIM / 16);
            pack_fm<<<(int)((nch + 255) / 256), 256, 0, stream>>>(w, w8p, OUT_DIM, IN_DIM);
        }
        const int grid = (T_DIM / BM) * (OUT_DIM / BN);  // 1024
        gemm_i8_fm<<<grid, 512, 0, stream>>>(x8p, w8p, bias, alpha, beta, out);
    } else {
        const int grid = (T_DIM / 128) * (OUT_DIM / 128);  // 4096
        gemm_i8_fb<<<grid, 256, 0, stream>>>(x, w, bias, alpha, beta, out);
    }
}